// Round 11
// baseline (268.271 us; speedup 1.0000x reference)
//
#include <hip/hip_runtime.h>
#include <hip/hip_bf16.h>
#include <math.h>

constexpr int Rc  = 3;
constexpr int Fc  = 256;
constexpr int Hc  = 128;
constexpr int N0c = 16384;
constexpr int S1c = 16384;
constexpr int D1c = 4096;
constexpr int S2c = 4096;
constexpr int D2c = 512;
constexpr int KH1 = 4;
constexpr int KH2 = 16;

typedef __bf16 bf16x8 __attribute__((ext_vector_type(8)));
typedef __bf16 bf16x4 __attribute__((ext_vector_type(4)));
typedef float  f32x4  __attribute__((ext_vector_type(4)));

__device__ __forceinline__ void glds16(const void* g, void* l) {
  __builtin_amdgcn_global_load_lds(
      (const __attribute__((address_space(1))) void*)g,
      (__attribute__((address_space(3))) void*)l, 16, 0, 0);
}

__device__ __forceinline__ bf16x8 cvt2(const float4 a, const float4 b) {
  bf16x8 c;
  c[0] = (__bf16)a.x; c[1] = (__bf16)a.y; c[2] = (__bf16)a.z; c[3] = (__bf16)a.w;
  c[4] = (__bf16)b.x; c[5] = (__bf16)b.y; c[6] = (__bf16)b.z; c[7] = (__bf16)b.w;
  return c;
}

__device__ __forceinline__ bf16x8 cvt2v(const f32x4 a, const f32x4 b) {
  bf16x8 c;
  c[0] = (__bf16)a.x; c[1] = (__bf16)a.y; c[2] = (__bf16)a.z; c[3] = (__bf16)a.w;
  c[4] = (__bf16)b.x; c[5] = (__bf16)b.y; c[6] = (__bf16)b.z; c[7] = (__bf16)b.w;
  return c;
}

__device__ __forceinline__ unsigned short bfbits(float v) {
  __bf16 b = (__bf16)v; unsigned short u;
  __builtin_memcpy(&u, &b, 2); return u;
}

// ---------------------------------------------------------------------------
// wpack: fp32 weight [rows x 128] -> packed bf16 hi/lo B-panels (GEMM-LDS
// image). 12 tiles: 0-3 w1top, 4-7 w1bot, 8-9 w2P, 10-11 w2Q; half=1 = bf16
// residual. Block (0,0) zeroes esum.
// ---------------------------------------------------------------------------
__global__ __launch_bounds__(256, 2)
void wpack(const float* __restrict__ w1, const float* __restrict__ w2,
           unsigned char* __restrict__ wp, float* __restrict__ esum) {
  const int tile = blockIdx.x, half = blockIdx.y, t = threadIdx.x;
  if (tile == 0 && half == 0 && t < 8) esum[t] = 0.f;
  const float* src; int row0;
  if (tile < 4)       { src = w1; row0 = tile * 64; }
  else if (tile < 8)  { src = w1; row0 = 256 + (tile - 4) * 64; }
  else if (tile < 10) { src = w2; row0 = (tile - 8) * 64; }
  else                { src = w2; row0 = 128 + (tile - 10) * 64; }
  unsigned char* dst = wp + ((size_t)half * 12 + tile) * 16384;
  __shared__ float sm[64][132];
  {
    const int r = t >> 2, c0 = (t & 3) * 32;
#pragma unroll
    for (int j = 0; j < 8; j++)
      *(float4*)&sm[r][c0 + 4 * j] = *(const float4*)(src + (size_t)(row0 + r) * 128 + c0 + 4 * j);
  }
  __syncthreads();
  if (t < 128) {
    const int n = t;
#pragma unroll
    for (int ch = 0; ch < 8; ch++) {
      bf16x8 o;
#pragma unroll
      for (int e = 0; e < 8; e++) {
        float v = sm[ch * 8 + e][n];
        __bf16 h = (__bf16)v;
        o[e] = half ? (__bf16)(v - (float)h) : h;
      }
      *(bf16x8*)(dst + n * 128 + ((ch ^ (n & 7)) * 16)) = o;
    }
  }
}

// ---------------------------------------------------------------------------
// gg0: xgw = gather(feat; srcn.d2s1) @ (w1t_h+w1t_l) -> packed B panel.
// ---------------------------------------------------------------------------
__global__ __launch_bounds__(256, 3)
void gg0(const float* __restrict__ feat, const int* __restrict__ srcn,
         const int* __restrict__ d2s1, const unsigned char* __restrict__ wp,
         unsigned char* __restrict__ xgwp) {
  const int rel = blockIdx.y, bx = blockIdx.x, s0 = bx * 64;
  const unsigned char* Bh = wp;
  const unsigned char* Bl = wp + (size_t)12 * 16384;

  const int t = threadIdx.x, lane = t & 63, w = t >> 6;
  const int mh = w >> 1, nh = w & 1;

  __shared__ __bf16 Asm[64 * 64];
  __shared__ __bf16 Bhs[128 * 64];
  __shared__ __bf16 Bls[128 * 64];

  const int arow = t >> 2, ak0 = (t & 3) * 16;
  const int row = s0 + arow;
  const size_t arowg = (size_t)srcn[rel * N0c + d2s1[(size_t)rel * S1c + row]];
  const float* aptr = feat + arowg * Fc + ak0;
  const int ac0 = ak0 >> 3;
  __bf16* asw0 = &Asm[arow * 64 + ((ac0    ) ^ (arow & 7)) * 8];
  __bf16* asw1 = &Asm[arow * 64 + ((ac0 + 1) ^ (arow & 7)) * 8];

  float4 a[16];
#pragma unroll
  for (int tl = 0; tl < 4; tl++)
#pragma unroll
    for (int j = 0; j < 4; j++) a[tl * 4 + j] = *(const float4*)(aptr + tl * 64 + 4 * j);

  f32x4 acc[2][4] = {};

  for (int tl = 0; tl < 4; ++tl) {
    asm volatile("s_waitcnt lgkmcnt(0)" ::: "memory");
    __builtin_amdgcn_s_barrier();
    __builtin_amdgcn_sched_barrier(0);
    {
      const unsigned char* bh = Bh + (size_t)tl * 16384 + w * 4096 + lane * 16;
      const unsigned char* bl = Bl + (size_t)tl * 16384 + w * 4096 + lane * 16;
      char* dh = (char*)Bhs + w * 4096;
      char* dl = (char*)Bls + w * 4096;
#pragma unroll
      for (int i = 0; i < 4; i++) glds16(bh + i * 1024, dh + i * 1024);
#pragma unroll
      for (int i = 0; i < 4; i++) glds16(bl + i * 1024, dl + i * 1024);
    }
    *(bf16x8*)asw0 = cvt2(a[tl * 4 + 0], a[tl * 4 + 1]);
    *(bf16x8*)asw1 = cvt2(a[tl * 4 + 2], a[tl * 4 + 3]);
    asm volatile("s_waitcnt vmcnt(0) lgkmcnt(0)" ::: "memory");
    __builtin_amdgcn_s_barrier();
    __builtin_amdgcn_sched_barrier(0);
#pragma unroll
    for (int ks = 0; ks < 2; ks++) {
      const int ch = ks * 4 + (lane >> 4);
      bf16x8 af[2], bh[4], bl[4];
#pragma unroll
      for (int mi = 0; mi < 2; mi++) {
        int r = mh * 32 + mi * 16 + (lane & 15);
        af[mi] = *(const bf16x8*)&Asm[r * 64 + ((ch ^ (r & 7)) * 8)];
      }
#pragma unroll
      for (int ni = 0; ni < 4; ni++) {
        int n = nh * 64 + ni * 16 + (lane & 15);
        bh[ni] = *(const bf16x8*)&Bhs[n * 64 + ((ch ^ (n & 7)) * 8)];
        bl[ni] = *(const bf16x8*)&Bls[n * 64 + ((ch ^ (n & 7)) * 8)];
      }
#pragma unroll
      for (int mi = 0; mi < 2; mi++)
#pragma unroll
        for (int ni = 0; ni < 4; ni++) {
          acc[mi][ni] = __builtin_amdgcn_mfma_f32_16x16x32_bf16(af[mi], bh[ni], acc[mi][ni], 0, 0, 0);
          acc[mi][ni] = __builtin_amdgcn_mfma_f32_16x16x32_bf16(af[mi], bl[ni], acc[mi][ni], 0, 0, 0);
        }
    }
  }
  unsigned char* tile = xgwp + ((size_t)(rel * (S1c >> 6) + bx)) * 16384;
#pragma unroll
  for (int mi = 0; mi < 2; mi++)
#pragma unroll
    for (int ni = 0; ni < 4; ni++) {
      const int sl0 = mh * 32 + mi * 16 + (lane >> 4) * 4;
      const int n = nh * 64 + ni * 16 + (lane & 15);
      const int ch = sl0 >> 3, e0 = sl0 & 7, cs = ch ^ (n & 7);
      ushort4 u;
      u.x = bfbits(acc[mi][ni][0]); u.y = bfbits(acc[mi][ni][1]);
      u.z = bfbits(acc[mi][ni][2]); u.w = bfbits(acc[mi][ni][3]);
      *(ushort4*)(tile + n * 128 + cs * 16 + e0 * 2) = u;
    }
}

// ---------------------------------------------------------------------------
// big1p: blocks 0-767 -> aggP[kh] = dif1 @ xgw (XCD swizzle, K=128 macro-tile
// wave-contiguous 512B burst NONTEMPORAL A-reads, A-LDS/B-LDS double-buffer,
// counted vmcnt).  blocks 768-959 -> xdw projection.
// ---------------------------------------------------------------------------
__global__ __launch_bounds__(256, 3)
void big1p(const float* __restrict__ dif1, const unsigned char* __restrict__ xgwp,
           float* __restrict__ aggP, const float* __restrict__ feat,
           const int* __restrict__ srcn, const int* __restrict__ d2d1,
           const unsigned char* __restrict__ wp, float* __restrict__ xdw) {
  __shared__ char lds[49152];
  const int t = threadIdx.x, lane = t & 63, w = t >> 6;
  const int mh = w >> 1, nh = w & 1;

  if (blockIdx.x < 768) {
    __bf16* Abuf = (__bf16*)lds;
    __bf16* Bbuf = (__bf16*)(lds + 16384);
    const int F = blockIdx.x;
    const int xcd = F & 7, r = F >> 3;
    const int sub = r >> 5, m = r & 31;
    const int h = xcd + 8 * sub;
    const int g2 = h >> 1;
    const int rel = g2 >> 2, kh = g2 & 3;
    const int m0 = ((h & 1) * 32 + m) * 64;
    constexpr int NP = 64;
    constexpr int NM = 32;

    const unsigned char* Bt = xgwp + ((size_t)rel * 256 + (size_t)kh * NP) * 16384;
    float* Cg = aggP + (((size_t)kh * Rc + rel) * D1c + m0) * 128;

    const int lst = (lane & 31) >> 4;
    const int lr2 = lane >> 5;
    const int fo  = (lane & 31) * 4;
    const int ch  = (fo & 63) >> 3;
    const int eo  = fo & 7;
    const float* aW = dif1 + ((size_t)(rel * D1c + m0 + w * 16 + lr2)) * S1c
                    + (size_t)kh * 4096 + fo;
    const unsigned char* bsrc = Bt + w * 4096 + lane * 16;

    f32x4 acc[2][4] = {};
    f32x4 a0[8], a1[8];

#define LOAD_A(ARR, M_) do { _Pragma("unroll") \
    for (int ri = 0; ri < 8; ri++) \
      ARR[ri] = __builtin_nontemporal_load( \
          (const f32x4*)(aW + (size_t)ri * 2 * S1c + (size_t)(M_) * 128)); \
  } while (0)

#define WRITE_A(ARR, NBUF) do { if (lst == (NBUF)) { _Pragma("unroll") \
    for (int ri = 0; ri < 8; ri++) { \
      const int row_ = w * 16 + ri * 2 + lr2; \
      bf16x4 cv_; \
      cv_[0] = (__bf16)ARR[ri].x; cv_[1] = (__bf16)ARR[ri].y; \
      cv_[2] = (__bf16)ARR[ri].z; cv_[3] = (__bf16)ARR[ri].w; \
      *(bf16x4*)&Abuf[(NBUF) * 4096 + row_ * 64 + ((ch ^ (row_ & 7)) * 8) + eo] = cv_; \
    } } } while (0)

    LOAD_A(a0, 0);
    {
      char* bd = (char*)Bbuf + w * 4096;
#pragma unroll
      for (int i = 0; i < 4; i++) glds16(bsrc + i * 1024, bd + i * 1024);
    }
    WRITE_A(a0, 0);
    LOAD_A(a1, 1);

#pragma unroll 1
    for (int g = 0; g < NP; ++g) {
      const int buf = g & 1, nbuf = buf ^ 1;
      asm volatile("s_waitcnt lgkmcnt(0)" ::: "memory");
      __builtin_amdgcn_s_barrier();
      __builtin_amdgcn_sched_barrier(0);
      if (g + 1 < NP) {
        const unsigned char* bs = bsrc + (size_t)(g + 1) * 16384;
        char* bd = (char*)Bbuf + nbuf * 16384 + w * 4096;
#pragma unroll
        for (int i = 0; i < 4; i++) glds16(bs + i * 1024, bd + i * 1024);
      }
      if (g + 1 < NP) {
        const int mw = (g + 1) >> 1;
        if ((mw & 1) == 0) { WRITE_A(a0, nbuf); }
        else               { WRITE_A(a1, nbuf); }
      }
      if (g & 1) {
        const int mn = (g + 3) >> 1;
        if (mn < NM) {
          if ((mn & 1) == 0) { LOAD_A(a0, mn); }
          else               { LOAD_A(a1, mn); }
        }
      }
      if (g < NP - 2)
        asm volatile("s_waitcnt vmcnt(12) lgkmcnt(0)" ::: "memory");
      else if (g == NP - 2)
        asm volatile("s_waitcnt vmcnt(4) lgkmcnt(0)" ::: "memory");
      else
        asm volatile("s_waitcnt vmcnt(0) lgkmcnt(0)" ::: "memory");
      __builtin_amdgcn_s_barrier();
      __builtin_amdgcn_sched_barrier(0);
      const __bf16* Ac = Abuf + buf * 4096;
      const __bf16* Bc = Bbuf + buf * 8192;
#pragma unroll
      for (int ks = 0; ks < 2; ks++) {
        const int cch = ks * 4 + (lane >> 4);
        bf16x8 af[2], bfr[4];
#pragma unroll
        for (int mi = 0; mi < 2; mi++) {
          int rr = mh * 32 + mi * 16 + (lane & 15);
          af[mi] = *(const bf16x8*)&Ac[rr * 64 + ((cch ^ (rr & 7)) * 8)];
        }
#pragma unroll
        for (int ni = 0; ni < 4; ni++) {
          int n = nh * 64 + ni * 16 + (lane & 15);
          bfr[ni] = *(const bf16x8*)&Bc[n * 64 + ((cch ^ (n & 7)) * 8)];
        }
#pragma unroll
        for (int mi = 0; mi < 2; mi++)
#pragma unroll
          for (int ni = 0; ni < 4; ni++)
            acc[mi][ni] = __builtin_amdgcn_mfma_f32_16x16x32_bf16(af[mi], bfr[ni], acc[mi][ni], 0, 0, 0);
      }
    }
#undef LOAD_A
#undef WRITE_A
#pragma unroll
    for (int mi = 0; mi < 2; mi++)
#pragma unroll
      for (int ni = 0; ni < 4; ni++) {
        const int col = nh * 64 + ni * 16 + (lane & 15);
#pragma unroll
        for (int j = 0; j < 4; j++) {
          const int rr = mh * 32 + mi * 16 + (lane >> 4) * 4 + j;
          Cg[(size_t)rr * 128 + col] = acc[mi][ni][j];
        }
      }
  } else {
    __bf16* Asm = (__bf16*)lds;
    __bf16* Bhs = (__bf16*)(lds + 8192);
    __bf16* Bls = (__bf16*)(lds + 24576);
    const int jb = blockIdx.x - 768;
    const int rel = jb >> 6, bx = jb & 63, s0 = bx * 64;
    const unsigned char* Bh = wp + (size_t)4 * 16384;
    const unsigned char* Bl = wp + (size_t)16 * 16384;

    const int arow = t >> 2, ak0 = (t & 3) * 16;
    const int row = s0 + arow;
    const size_t arowg = (size_t)srcn[rel * N0c + d2d1[(size_t)rel * D1c + row]];
    const float* aptr = feat + arowg * Fc + ak0;
    const int ac0 = ak0 >> 3;
    __bf16* asw0 = &Asm[arow * 64 + ((ac0    ) ^ (arow & 7)) * 8];
    __bf16* asw1 = &Asm[arow * 64 + ((ac0 + 1) ^ (arow & 7)) * 8];

    float4 a[16];
#pragma unroll
    for (int tl = 0; tl < 4; tl++)
#pragma unroll
      for (int j = 0; j < 4; j++) a[tl * 4 + j] = *(const float4*)(aptr + tl * 64 + 4 * j);

    f32x4 acc[2][4] = {};
    for (int tl = 0; tl < 4; ++tl) {
      asm volatile("s_waitcnt lgkmcnt(0)" ::: "memory");
      __builtin_amdgcn_s_barrier();
      __builtin_amdgcn_sched_barrier(0);
      {
        const unsigned char* bh = Bh + (size_t)tl * 16384 + w * 4096 + lane * 16;
        const unsigned char* bl = Bl + (size_t)tl * 16384 + w * 4096 + lane * 16;
        char* dh = (char*)Bhs + w * 4096;
        char* dl = (char*)Bls + w * 4096;
#pragma unroll
        for (int i = 0; i < 4; i++) glds16(bh + i * 1024, dh + i * 1024);
#pragma unroll
        for (int i = 0; i < 4; i++) glds16(bl + i * 1024, dl + i * 1024);
      }
      *(bf16x8*)asw0 = cvt2(a[tl * 4 + 0], a[tl * 4 + 1]);
      *(bf16x8*)asw1 = cvt2(a[tl * 4 + 2], a[tl * 4 + 3]);
      asm volatile("s_waitcnt vmcnt(0) lgkmcnt(0)" ::: "memory");
      __builtin_amdgcn_s_barrier();
      __builtin_amdgcn_sched_barrier(0);
#pragma unroll
      for (int ks = 0; ks < 2; ks++) {
        const int ch = ks * 4 + (lane >> 4);
        bf16x8 af[2], bh[4], bl[4];
#pragma unroll
        for (int mi = 0; mi < 2; mi++) {
          int r = mh * 32 + mi * 16 + (lane & 15);
          af[mi] = *(const bf16x8*)&Asm[r * 64 + ((ch ^ (r & 7)) * 8)];
        }
#pragma unroll
        for (int ni = 0; ni < 4; ni++) {
          int n = nh * 64 + ni * 16 + (lane & 15);
          bh[ni] = *(const bf16x8*)&Bhs[n * 64 + ((ch ^ (n & 7)) * 8)];
          bl[ni] = *(const bf16x8*)&Bls[n * 64 + ((ch ^ (n & 7)) * 8)];
        }
#pragma unroll
        for (int mi = 0; mi < 2; mi++)
#pragma unroll
          for (int ni = 0; ni < 4; ni++) {
            acc[mi][ni] = __builtin_amdgcn_mfma_f32_16x16x32_bf16(af[mi], bh[ni], acc[mi][ni], 0, 0, 0);
            acc[mi][ni] = __builtin_amdgcn_mfma_f32_16x16x32_bf16(af[mi], bl[ni], acc[mi][ni], 0, 0, 0);
          }
      }
    }
#pragma unroll
    for (int mi = 0; mi < 2; mi++)
#pragma unroll
      for (int ni = 0; ni < 4; ni++) {
        const int col = nh * 64 + ni * 16 + (lane & 15);
#pragma unroll
        for (int j = 0; j < 4; j++) {
          const int rr = mh * 32 + mi * 16 + (lane >> 4) * 4 + j;
          xdw[((size_t)rel * D1c + s0 + rr) * 128 + col] = acc[mi][ni][j];
        }
      }
  }
}

// ---------------------------------------------------------------------------
// gemm_big: C_partial[kh] = A[rel][m][k-slice] @ Bpanel  (GEMM2; NT A-reads)
// ---------------------------------------------------------------------------
__global__ __launch_bounds__(256, 3)
void gemm_big(const float* __restrict__ A, const unsigned char* __restrict__ Bp,
              float* __restrict__ C, int M, int KTOT, int KH) {
  const int rel = blockIdx.z, kh = blockIdx.y, m0 = blockIdx.x * 64;
  const int t = threadIdx.x, lane = t & 63, w = t >> 6;
  const int KB = KTOT / KH, NT = KB >> 6;
  const int mh = w >> 1, nh = w & 1;

  const float* Ag = A + ((size_t)rel * M + m0) * KTOT + (size_t)kh * KB;
  const unsigned char* Bt = Bp + ((size_t)rel * (KTOT >> 6) + (size_t)kh * NT) * 16384;
  float* Cg = C + (((size_t)kh * Rc + rel) * M + m0) * 128;

  __shared__ __bf16 Asm[64 * 64];
  __shared__ __bf16 Bsm[2][128 * 64];

  f32x4 acc[2][4] = {};
  const int arow = t >> 2, ak0 = (t & 3) * 16;
  const float* aptr = Ag + (size_t)arow * KTOT + ak0;
  const int ac0 = ak0 >> 3;
  __bf16* asw0 = &Asm[arow * 64 + ((ac0    ) ^ (arow & 7)) * 8];
  __bf16* asw1 = &Asm[arow * 64 + ((ac0 + 1) ^ (arow & 7)) * 8];
  const unsigned char* bsrc = Bt + w * 4096 + lane * 16;

  f32x4 a0[4], a1[4];
#pragma unroll
  for (int j = 0; j < 4; j++) a0[j] = __builtin_nontemporal_load((const f32x4*)(aptr + 4 * j));
  {
    char* bd = (char*)Bsm[0] + w * 4096;
#pragma unroll
    for (int i = 0; i < 4; i++) glds16(bsrc + i * 1024, bd + i * 1024);
  }

  for (int tl = 0; tl < NT; ++tl) {
    const int cur = tl & 1;
    asm volatile("s_waitcnt lgkmcnt(0)" ::: "memory");
    __builtin_amdgcn_s_barrier();
    __builtin_amdgcn_sched_barrier(0);
    if (tl + 1 < NT) {
      const unsigned char* bs = bsrc + (size_t)(tl + 1) * 16384;
      char* bd = (char*)Bsm[cur ^ 1] + w * 4096;
#pragma unroll
      for (int i = 0; i < 4; i++) glds16(bs + i * 1024, bd + i * 1024);
      const float* ap = aptr + (size_t)(tl + 1) * 64;
#pragma unroll
      for (int j = 0; j < 4; j++) a1[j] = __builtin_nontemporal_load((const f32x4*)(ap + 4 * j));
    }
    *(bf16x8*)asw0 = cvt2v(a0[0], a0[1]);
    *(bf16x8*)asw1 = cvt2v(a0[2], a0[3]);
    if (tl + 1 < NT)
      asm volatile("s_waitcnt vmcnt(8) lgkmcnt(0)" ::: "memory");
    else
      asm volatile("s_waitcnt vmcnt(0) lgkmcnt(0)" ::: "memory");
    __builtin_amdgcn_s_barrier();
    __builtin_amdgcn_sched_barrier(0);
    const __bf16* Bc = Bsm[cur];
#pragma unroll
    for (int ks = 0; ks < 2; ks++) {
      const int ch = ks * 4 + (lane >> 4);
      bf16x8 af[2], bfr[4];
#pragma unroll
      for (int mi = 0; mi < 2; mi++) {
        int r = mh * 32 + mi * 16 + (lane & 15);
        af[mi] = *(const bf16x8*)&Asm[r * 64 + ((ch ^ (r & 7)) * 8)];
      }
#pragma unroll
      for (int ni = 0; ni < 4; ni++) {
        int n = nh * 64 + ni * 16 + (lane & 15);
        bfr[ni] = *(const bf16x8*)&Bc[n * 64 + ((ch ^ (n & 7)) * 8)];
      }
#pragma unroll
      for (int mi = 0; mi < 2; mi++)
#pragma unroll
        for (int ni = 0; ni < 4; ni++)
          acc[mi][ni] = __builtin_amdgcn_mfma_f32_16x16x32_bf16(af[mi], bfr[ni], acc[mi][ni], 0, 0, 0);
    }
#pragma unroll
    for (int j = 0; j < 4; j++) a0[j] = a1[j];
  }
#pragma unroll
  for (int mi = 0; mi < 2; mi++)
#pragma unroll
    for (int ni = 0; ni < 4; ni++) {
      const int col = nh * 64 + ni * 16 + (lane & 15);
#pragma unroll
      for (int j = 0; j < 4; j++) {
        const int r = mh * 32 + mi * 16 + (lane >> 4) * 4 + j;
        Cg[(size_t)r * 128 + col] = acc[mi][ni][j];
      }
    }
}

// ---------------------------------------------------------------------------
// c1_l2: FUSED combine1 + BOTH layer-2 projections.  B panels double-buffered
// and PRE-ISSUED: phase-0 glds at kernel entry (hidden under the 40-load
// h-build), later phases one ahead with counted vmcnt(8).  NT h-build reads.
// ---------------------------------------------------------------------------
__global__ __launch_bounds__(256, 1)
void c1_l2(const float* __restrict__ aggP, const float* __restrict__ xdw,
           const float* __restrict__ attv, const unsigned char* __restrict__ wp,
           float* __restrict__ escore1, float* __restrict__ esum,
           float* __restrict__ P, float* __restrict__ Q) {
  const int rel = blockIdx.y, d0 = blockIdx.x * 64;
  const int t = threadIdx.x, lane = t & 63, w = t >> 6;
  const int mh = w >> 1, nh = w & 1;

  __shared__ __bf16 Asm[64 * 128];       // 16 KB
  __shared__ __bf16 Bhs[2][128 * 64];    // 32 KB
  __shared__ __bf16 Bls[2][128 * 64];    // 32 KB
  __shared__ float  sred[64];

  // ---- issue phase-0 B panels immediately (addresses independent) ----
  {
    const unsigned char* bh = wp + (size_t)8 * 16384 + w * 4096 + lane * 16;
    const unsigned char* bl = wp + (size_t)20 * 16384 + w * 4096 + lane * 16;
    char* dh = (char*)Bhs[0] + w * 4096;
    char* dl = (char*)Bls[0] + w * 4096;
#pragma unroll
    for (int i = 0; i < 4; i++) glds16(bh + i * 1024, dh + i * 1024);
#pragma unroll
    for (int i = 0; i < 4; i++) glds16(bl + i * 1024, dl + i * 1024);
  }

  // ---- h-build (NT: aggP/xdw are read-once) ----
  const int r = t >> 2, c0 = (t & 3) * 32;
  f32x4 x0[8];
  {
    const size_t base = ((size_t)rel * D1c + d0 + r) * 128 + c0;
#pragma unroll
    for (int j = 0; j < 8; j++)
      x0[j] = __builtin_nontemporal_load((const f32x4*)(xdw + base + 4 * j));
#pragma unroll
    for (int p2 = 0; p2 < KH1; p2++) {
      const float* ap = aggP + (((size_t)p2 * Rc + rel) * D1c + d0 + r) * 128 + c0;
#pragma unroll
      for (int j = 0; j < 8; j++) {
        f32x4 u = __builtin_nontemporal_load((const f32x4*)(ap + 4 * j));
        x0[j] += u;
      }
    }
  }
  float sp = 0.f;
#pragma unroll
  for (int j = 0; j < 8; j++) {
    sp += x0[j].x * attv[c0 + 4 * j]     + x0[j].y * attv[c0 + 4 * j + 1]
        + x0[j].z * attv[c0 + 4 * j + 2] + x0[j].w * attv[c0 + 4 * j + 3];
  }
  sp += __shfl_xor(sp, 1); sp += __shfl_xor(sp, 2);
  const float e = expf(sp);
  if ((t & 3) == 0) { escore1[(size_t)rel * D1c + d0 + r] = e; sred[r] = e; }
  const int ch0 = (t & 3) * 4;
#pragma unroll
  for (int q = 0; q < 4; q++) {
    *(bf16x8*)&Asm[r * 128 + (((ch0 + q) ^ (r & 7)) * 8)] = cvt2v(x0[2 * q], x0[2 * q + 1]);
  }
  __syncthreads();
  if (t < 64) {
    float v = sred[t];
    v += __shfl_down(v, 32); v += __shfl_down(v, 16); v += __shfl_down(v, 8);
    v += __shfl_down(v, 4);  v += __shfl_down(v, 2);  v += __shfl_down(v, 1);
    if (t == 0) atomicAdd(esum + rel, v);
  }

  // ---- 4 pipelined GEMM phases: p = z*2+tl ----
  f32x4 accP[2][4] = {}, accQ[2][4] = {};
#pragma unroll
  for (int p = 0; p < 4; ++p) {
    const int buf = p & 1;
    if (p) {
      asm volatile("s_waitcnt lgkmcnt(0)" ::: "memory");
      __builtin_amdgcn_s_barrier();
      __builtin_amdgcn_sched_barrier(0);
    }
    if (p < 3) {
      const unsigned char* bh = wp + (size_t)(8 + p + 1) * 16384 + w * 4096 + lane * 16;
      const unsigned char* bl = wp + (size_t)(20 + p + 1) * 16384 + w * 4096 + lane * 16;
      char* dh = (char*)Bhs[buf ^ 1] + w * 4096;
      char* dl = (char*)Bls[buf ^ 1] + w * 4096;
#pragma unroll
      for (int i = 0; i < 4; i++) glds16(bh + i * 1024, dh + i * 1024);
#pragma unroll
      for (int i = 0; i < 4; i++) glds16(bl + i * 1024, dl + i * 1024);
    }
    if (p < 3)
      asm volatile("s_waitcnt vmcnt(8) lgkmcnt(0)" ::: "memory");
    else
      asm volatile("s_waitcnt vmcnt(0) lgkmcnt(0)" ::: "memory");
    __builtin_amdgcn_s_barrier();
    __builtin_amdgcn_sched_barrier(0);
    const int z = p >> 1, tl = p & 1;
    f32x4 (*acc)[4] = z ? accQ : accP;
#pragma unroll
    for (int ks = 0; ks < 2; ks++) {
      const int lch = ks * 4 + (lane >> 4);
      const int ch  = tl * 8 + lch;
      bf16x8 af[2], bh[4], bl[4];
#pragma unroll
      for (int mi = 0; mi < 2; mi++) {
        int rr = mh * 32 + mi * 16 + (lane & 15);
        af[mi] = *(const bf16x8*)&Asm[rr * 128 + ((ch ^ (rr & 7)) * 8)];
      }
#pragma unroll
      for (int ni = 0; ni < 4; ni++) {
        int n = nh * 64 + ni * 16 + (lane & 15);
        bh[ni] = *(const bf16x8*)&Bhs[buf][n * 64 + ((lch ^ (n & 7)) * 8)];
        bl[ni] = *(const bf16x8*)&Bls[buf][n * 64 + ((lch ^ (n & 7)) * 8)];
      }
#pragma unroll
      for (int mi = 0; mi < 2; mi++)
#pragma unroll
        for (int ni = 0; ni < 4; ni++) {
          acc[mi][ni] = __builtin_amdgcn_mfma_f32_16x16x32_bf16(af[mi], bh[ni], acc[mi][ni], 0, 0, 0);
          acc[mi][ni] = __builtin_amdgcn_mfma_f32_16x16x32_bf16(af[mi], bl[ni], acc[mi][ni], 0, 0, 0);
        }
    }
  }
#pragma unroll
  for (int mi = 0; mi < 2; mi++)
#pragma unroll
    for (int ni = 0; ni < 4; ni++) {
      const int col = nh * 64 + ni * 16 + (lane & 15);
#pragma unroll
      for (int j = 0; j < 4; j++) {
        const int rr = mh * 32 + mi * 16 + (lane >> 4) * 4 + j;
        P[((size_t)rel * D1c + d0 + rr) * 128 + col] = accP[mi][ni][j];
        Q[((size_t)rel * D1c + d0 + rr) * 128 + col] = accQ[mi][ni][j];
      }
    }
}

// ---------------------------------------------------------------------------
// pgpack: PG panel <- gather P rows via d2s2, scale by att1, bf16 packed.
// ---------------------------------------------------------------------------
__global__ __launch_bounds__(256, 2)
void pgpack(const float* __restrict__ P, const int* __restrict__ d2s2,
            const float* __restrict__ escore1, const float* __restrict__ esum,
            unsigned char* __restrict__ PGp) {
  const int rel = blockIdx.y, kb = blockIdx.x, t = threadIdx.x;
  const float inv1 = 1.0f / esum[rel];
  __shared__ __bf16 sm[64][136];
  {
    const int kl = t >> 2, c0 = (t & 3) * 32;
    const int sr = d2s2[rel * S2c + kb * 64 + kl];
    const float sc = escore1[(size_t)rel * D1c + sr] * inv1;
    const float4* p = (const float4*)(P + ((size_t)rel * D1c + sr) * 128 + c0);
#pragma unroll
    for (int j = 0; j < 4; j++) {
      float4 v0 = p[2 * j], v1 = p[2 * j + 1];
      v0.x *= sc; v0.y *= sc; v0.z *= sc; v0.w *= sc;
      v1.x *= sc; v1.y *= sc; v1.z *= sc; v1.w *= sc;
      *(bf16x8*)&sm[kl][c0 + 8 * j] = cvt2(v0, v1);
    }
  }
  __syncthreads();
  if (t < 128) {
    const int n = t;
    unsigned char* dst = PGp + ((size_t)(rel * (S2c >> 6) + kb)) * 16384;
#pragma unroll
    for (int ch = 0; ch < 8; ch++) {
      bf16x8 o;
#pragma unroll
      for (int e = 0; e < 8; e++) o[e] = sm[ch * 8 + e][n];
      *(bf16x8*)(dst + n * 128 + ((ch ^ (n & 7)) * 16)) = o;
    }
  }
}

// ---------------------------------------------------------------------------
// combine2: h2 = sum_kh2 aggP2 + att1[qr]*Q[qr] ; e2 = exp(h2 . attv)
// 4 rows/block (384 blocks) for latency hiding; NT aggP2 reads.
// ---------------------------------------------------------------------------
__global__ __launch_bounds__(128, 4)
void combine2(const float* __restrict__ aggP2, const float* __restrict__ Q,
              const int* __restrict__ d2d2, const float* __restrict__ attv,
              const float* __restrict__ escore1, const float* __restrict__ esum,
              float* __restrict__ h2, float* __restrict__ escore2) {
  const int rel = blockIdx.y, d0 = blockIdx.x * 4, t = threadIdx.x;
  const float inv1 = 1.0f / esum[rel];
  float acc[4];
#pragma unroll
  for (int i = 0; i < 4; i++) {
    const int d = d0 + i;
    const int qr = d2d2[rel * D2c + d];
    const float qs = escore1[(size_t)rel * D1c + qr] * inv1;
    float v = Q[((size_t)rel * D1c + qr) * 128 + t] * qs;
#pragma unroll
    for (int p = 0; p < KH2; p++)
      v += __builtin_nontemporal_load(
          &aggP2[(((size_t)p * Rc + rel) * D2c + d) * 128 + t]);
    acc[i] = v;
    h2[((size_t)rel * D2c + d) * 128 + t] = v;
  }
  const float avt = attv[t];
  __shared__ float sred[2][4];
#pragma unroll
  for (int i = 0; i < 4; i++) {
    float p = acc[i] * avt;
    p += __shfl_down(p, 32); p += __shfl_down(p, 16); p += __shfl_down(p, 8);
    p += __shfl_down(p, 4);  p += __shfl_down(p, 2);  p += __shfl_down(p, 1);
    if ((t & 63) == 0) sred[t >> 6][i] = p;
  }
  __syncthreads();
  if (t < 4) {
    const float e2 = expf(sred[0][t] + sred[1][t]);
    escore2[rel * D2c + d0 + t] = e2;
    float v = e2;
    v += __shfl_down(v, 2); v += __shfl_down(v, 1);
    if (t == 0) atomicAdd((float*)esum + 4 + rel, v);
  }
}

// ---------------------------------------------------------------------------
// k9: summed = sum_r h2 * att2 ; l2-normalize; logits = normed@cw; softmax
// ---------------------------------------------------------------------------
__global__ __launch_bounds__(128, 4)
void k9_final(const float* __restrict__ h2, const float* __restrict__ escore2,
              const float* __restrict__ esum, const float* __restrict__ cw,
              float* __restrict__ out) {
  const int d = blockIdx.x, t = threadIdx.x;
  float v = 0.f;
#pragma unroll
  for (int r = 0; r < Rc; r++) {
    const float att = escore2[r * D2c + d] / esum[4 + r];
    v += h2[((size_t)r * D2c + d) * Hc + t] * att;
  }
  float ss = v * v;
  ss += __shfl_down(ss, 32); ss += __shfl_down(ss, 16); ss += __shfl_down(ss, 8);
  ss += __shfl_down(ss, 4);  ss += __shfl_down(ss, 2);  ss += __shfl_down(ss, 1);
  __shared__ float sr[3][2];
  if ((t & 63) == 0) sr[0][t >> 6] = ss;
  __syncthreads();
  const float tot = sr[0][0] + sr[0][1];
  const float inv = rsqrtf(fmaxf(tot, 1e-12f));
  const float nv = v * inv;
  float p0 = nv * cw[t * 2], p1 = nv * cw[t * 2 + 1];
  p0 += __shfl_down(p0, 32); p0 += __shfl_down(p0, 16); p0 += __shfl_down(p0, 8);
  p0 += __shfl_down(p0, 4);  p0 += __shfl_down(p0, 2);  p0 += __shfl_down(p0, 1);
  p1 += __shfl_down(p1, 32); p1 += __shfl_down(p1, 16); p1 += __shfl_down(p1, 8);
  p1 += __shfl_down(p1, 4);  p1 += __shfl_down(p1, 2);  p1 += __shfl_down(p1, 1);
  if ((t & 63) == 0) { sr[1][t >> 6] = p0; sr[2][t >> 6] = p1; }
  __syncthreads();
  if (t == 0) {
    const float l0 = sr[1][0] + sr[1][1];
    const float l1 = sr[2][0] + sr[2][1];
    const float m = fmaxf(l0, l1);
    const float e0 = expf(l0 - m), e1 = expf(l1 - m);
    const float is = 1.0f / (e0 + e1);
    out[d * 2 + 0] = e0 * is;
    out[d * 2 + 1] = e1 * is;
  }
}

// ---------------------------------------------------------------------------
extern "C" void kernel_launch(void* const* d_in, const int* in_sizes, int n_in,
                              void* d_out, int out_size, void* d_ws, size_t ws_size,
                              hipStream_t stream) {
  (void)in_sizes; (void)n_in; (void)out_size; (void)ws_size;
  const float* feat = (const float*)d_in[0];
  const int*   srcn = (const int*)d_in[1];
  const int*   d2s1 = (const int*)d_in[2];
  const int*   d2d1 = (const int*)d_in[3];
  const float* dif1 = (const float*)d_in[4];
  const int*   d2s2 = (const int*)d_in[5];
  const int*   d2d2 = (const int*)d_in[6];
  const float* dif2 = (const float*)d_in[7];
  const float* w1   = (const float*)d_in[8];
  const float* w2   = (const float*)d_in[9];
  // d_in[10] relation_vectors: softmax-invariant constant -> unused.
  const float* attv = (const float*)d_in[11];
  const float* cw   = (const float*)d_in[12];
  float* out = (float*)d_out;

  char* p = (char*)d_ws;
  auto take = [&](size_t n) { char* r = p; p += (n + 255) & ~(size_t)255; return r; };
  unsigned char* wp   = (unsigned char*)take(24 * 16384);
  unsigned char* xgwp = (unsigned char*)take((size_t)Rc * 256 * 16384);   // 12.6 MB (reused as P|Q)
  float* xdw    = (float*)take((size_t)Rc * D1c * 128 * 4);
  float* aggP   = (float*)take((size_t)KH1 * Rc * D1c * 128 * 4);         // 25.2 MB (reused as aggP2)
  float* escore1= (float*)take((size_t)Rc * D1c * 4);
  float* esum   = (float*)take(256);
  unsigned char* PGp = (unsigned char*)take((size_t)Rc * 64 * 16384);
  float* h2     = (float*)take((size_t)Rc * D2c * 128 * 4);
  float* escore2= (float*)take((size_t)Rc * D2c * 4);
  float* P = (float*)xgwp;                       // alias after big1p
  float* Q = P + (size_t)Rc * D1c * 128;
  float* aggP2 = aggP;                           // alias after c1_l2

  wpack<<<dim3(12, 2), 256, 0, stream>>>(w1, w2, wp, esum);
  gg0<<<dim3(256, Rc), 256, 0, stream>>>(feat, srcn, d2s1, wp, xgwp);
  big1p<<<960, 256, 0, stream>>>(dif1, xgwp, aggP, feat, srcn, d2d1, wp, xdw);
  c1_l2<<<dim3(D1c / 64, Rc), 256, 0, stream>>>(aggP, xdw, attv, wp, escore1, esum, P, Q);
  pgpack<<<dim3(S2c / 64, Rc), 256, 0, stream>>>(P, d2s2, escore1, esum, PGp);
  gemm_big<<<dim3(D2c / 64, KH2, Rc), 256, 0, stream>>>(dif2, PGp, aggP2, D2c, S2c, KH2);
  combine2<<<dim3(D2c / 4, Rc), 128, 0, stream>>>(aggP2, Q, d2d2, attv, escore1, esum, h2, escore2);
  k9_final<<<D2c, 128, 0, stream>>>(h2, escore2, esum, cw, out);
}

// Round 12
// 263.127 us; speedup vs baseline: 1.0195x; 1.0195x over previous
//
#include <hip/hip_runtime.h>
#include <hip/hip_bf16.h>
#include <math.h>

constexpr int Rc  = 3;
constexpr int Fc  = 256;
constexpr int Hc  = 128;
constexpr int N0c = 16384;
constexpr int S1c = 16384;
constexpr int D1c = 4096;
constexpr int S2c = 4096;
constexpr int D2c = 512;
constexpr int KH1 = 4;
constexpr int KH2 = 16;

typedef __bf16 bf16x8 __attribute__((ext_vector_type(8)));
typedef __bf16 bf16x4 __attribute__((ext_vector_type(4)));
typedef float  f32x4  __attribute__((ext_vector_type(4)));

__device__ __forceinline__ void glds16(const void* g, void* l) {
  __builtin_amdgcn_global_load_lds(
      (const __attribute__((address_space(1))) void*)g,
      (__attribute__((address_space(3))) void*)l, 16, 0, 0);
}

__device__ __forceinline__ bf16x8 cvt2(const float4 a, const float4 b) {
  bf16x8 c;
  c[0] = (__bf16)a.x; c[1] = (__bf16)a.y; c[2] = (__bf16)a.z; c[3] = (__bf16)a.w;
  c[4] = (__bf16)b.x; c[5] = (__bf16)b.y; c[6] = (__bf16)b.z; c[7] = (__bf16)b.w;
  return c;
}

__device__ __forceinline__ unsigned short bfbits(float v) {
  __bf16 b = (__bf16)v; unsigned short u;
  __builtin_memcpy(&u, &b, 2); return u;
}

// ---------------------------------------------------------------------------
// wpack: fp32 weight [rows x 128] -> packed bf16 hi/lo B-panels (GEMM-LDS
// image). 12 tiles: 0-3 w1top, 4-7 w1bot, 8-9 w2P, 10-11 w2Q; half=1 = bf16
// residual. Block (0,0) zeroes esum.
// ---------------------------------------------------------------------------
__global__ __launch_bounds__(256, 2)
void wpack(const float* __restrict__ w1, const float* __restrict__ w2,
           unsigned char* __restrict__ wp, float* __restrict__ esum) {
  const int tile = blockIdx.x, half = blockIdx.y, t = threadIdx.x;
  if (tile == 0 && half == 0 && t < 8) esum[t] = 0.f;
  const float* src; int row0;
  if (tile < 4)       { src = w1; row0 = tile * 64; }
  else if (tile < 8)  { src = w1; row0 = 256 + (tile - 4) * 64; }
  else if (tile < 10) { src = w2; row0 = (tile - 8) * 64; }
  else                { src = w2; row0 = 128 + (tile - 10) * 64; }
  unsigned char* dst = wp + ((size_t)half * 12 + tile) * 16384;
  __shared__ float sm[64][132];
  {
    const int r = t >> 2, c0 = (t & 3) * 32;
#pragma unroll
    for (int j = 0; j < 8; j++)
      *(float4*)&sm[r][c0 + 4 * j] = *(const float4*)(src + (size_t)(row0 + r) * 128 + c0 + 4 * j);
  }
  __syncthreads();
  if (t < 128) {
    const int n = t;
#pragma unroll
    for (int ch = 0; ch < 8; ch++) {
      bf16x8 o;
#pragma unroll
      for (int e = 0; e < 8; e++) {
        float v = sm[ch * 8 + e][n];
        __bf16 h = (__bf16)v;
        o[e] = half ? (__bf16)(v - (float)h) : h;
      }
      *(bf16x8*)(dst + n * 128 + ((ch ^ (n & 7)) * 16)) = o;
    }
  }
}

// ---------------------------------------------------------------------------
// gg0: xgw = gather(feat; srcn.d2s1) @ (w1t_h+w1t_l) -> packed B panel.
// ---------------------------------------------------------------------------
__global__ __launch_bounds__(256, 3)
void gg0(const float* __restrict__ feat, const int* __restrict__ srcn,
         const int* __restrict__ d2s1, const unsigned char* __restrict__ wp,
         unsigned char* __restrict__ xgwp) {
  const int rel = blockIdx.y, bx = blockIdx.x, s0 = bx * 64;
  const unsigned char* Bh = wp;
  const unsigned char* Bl = wp + (size_t)12 * 16384;

  const int t = threadIdx.x, lane = t & 63, w = t >> 6;
  const int mh = w >> 1, nh = w & 1;

  __shared__ __bf16 Asm[64 * 64];
  __shared__ __bf16 Bhs[128 * 64];
  __shared__ __bf16 Bls[128 * 64];

  const int arow = t >> 2, ak0 = (t & 3) * 16;
  const int row = s0 + arow;
  const size_t arowg = (size_t)srcn[rel * N0c + d2s1[(size_t)rel * S1c + row]];
  const float* aptr = feat + arowg * Fc + ak0;
  const int ac0 = ak0 >> 3;
  __bf16* asw0 = &Asm[arow * 64 + ((ac0    ) ^ (arow & 7)) * 8];
  __bf16* asw1 = &Asm[arow * 64 + ((ac0 + 1) ^ (arow & 7)) * 8];

  float4 a[16];
#pragma unroll
  for (int tl = 0; tl < 4; tl++)
#pragma unroll
    for (int j = 0; j < 4; j++) a[tl * 4 + j] = *(const float4*)(aptr + tl * 64 + 4 * j);

  f32x4 acc[2][4] = {};

  for (int tl = 0; tl < 4; ++tl) {
    asm volatile("s_waitcnt lgkmcnt(0)" ::: "memory");
    __builtin_amdgcn_s_barrier();
    __builtin_amdgcn_sched_barrier(0);
    {
      const unsigned char* bh = Bh + (size_t)tl * 16384 + w * 4096 + lane * 16;
      const unsigned char* bl = Bl + (size_t)tl * 16384 + w * 4096 + lane * 16;
      char* dh = (char*)Bhs + w * 4096;
      char* dl = (char*)Bls + w * 4096;
#pragma unroll
      for (int i = 0; i < 4; i++) glds16(bh + i * 1024, dh + i * 1024);
#pragma unroll
      for (int i = 0; i < 4; i++) glds16(bl + i * 1024, dl + i * 1024);
    }
    *(bf16x8*)asw0 = cvt2(a[tl * 4 + 0], a[tl * 4 + 1]);
    *(bf16x8*)asw1 = cvt2(a[tl * 4 + 2], a[tl * 4 + 3]);
    asm volatile("s_waitcnt vmcnt(0) lgkmcnt(0)" ::: "memory");
    __builtin_amdgcn_s_barrier();
    __builtin_amdgcn_sched_barrier(0);
#pragma unroll
    for (int ks = 0; ks < 2; ks++) {
      const int ch = ks * 4 + (lane >> 4);
      bf16x8 af[2], bh[4], bl[4];
#pragma unroll
      for (int mi = 0; mi < 2; mi++) {
        int r = mh * 32 + mi * 16 + (lane & 15);
        af[mi] = *(const bf16x8*)&Asm[r * 64 + ((ch ^ (r & 7)) * 8)];
      }
#pragma unroll
      for (int ni = 0; ni < 4; ni++) {
        int n = nh * 64 + ni * 16 + (lane & 15);
        bh[ni] = *(const bf16x8*)&Bhs[n * 64 + ((ch ^ (n & 7)) * 8)];
        bl[ni] = *(const bf16x8*)&Bls[n * 64 + ((ch ^ (n & 7)) * 8)];
      }
#pragma unroll
      for (int mi = 0; mi < 2; mi++)
#pragma unroll
        for (int ni = 0; ni < 4; ni++) {
          acc[mi][ni] = __builtin_amdgcn_mfma_f32_16x16x32_bf16(af[mi], bh[ni], acc[mi][ni], 0, 0, 0);
          acc[mi][ni] = __builtin_amdgcn_mfma_f32_16x16x32_bf16(af[mi], bl[ni], acc[mi][ni], 0, 0, 0);
        }
    }
  }
  unsigned char* tile = xgwp + ((size_t)(rel * (S1c >> 6) + bx)) * 16384;
#pragma unroll
  for (int mi = 0; mi < 2; mi++)
#pragma unroll
    for (int ni = 0; ni < 4; ni++) {
      const int sl0 = mh * 32 + mi * 16 + (lane >> 4) * 4;
      const int n = nh * 64 + ni * 16 + (lane & 15);
      const int ch = sl0 >> 3, e0 = sl0 & 7, cs = ch ^ (n & 7);
      ushort4 u;
      u.x = bfbits(acc[mi][ni][0]); u.y = bfbits(acc[mi][ni][1]);
      u.z = bfbits(acc[mi][ni][2]); u.w = bfbits(acc[mi][ni][3]);
      *(ushort4*)(tile + n * 128 + cs * 16 + e0 * 2) = u;
    }
}

// ---------------------------------------------------------------------------
// big1p: blocks 0-767 -> aggP[kh] = dif1 @ xgw (XCD swizzle, K=128 macro-tile
// wave-contiguous 512B burst NONTEMPORAL A-reads, A-LDS/B-LDS double-buffer,
// counted vmcnt).  blocks 768-959 -> xdw projection.
// ---------------------------------------------------------------------------
__global__ __launch_bounds__(256, 3)
void big1p(const float* __restrict__ dif1, const unsigned char* __restrict__ xgwp,
           float* __restrict__ aggP, const float* __restrict__ feat,
           const int* __restrict__ srcn, const int* __restrict__ d2d1,
           const unsigned char* __restrict__ wp, float* __restrict__ xdw) {
  __shared__ char lds[49152];
  const int t = threadIdx.x, lane = t & 63, w = t >> 6;
  const int mh = w >> 1, nh = w & 1;

  if (blockIdx.x < 768) {
    __bf16* Abuf = (__bf16*)lds;
    __bf16* Bbuf = (__bf16*)(lds + 16384);
    const int F = blockIdx.x;
    const int xcd = F & 7, r = F >> 3;
    const int sub = r >> 5, m = r & 31;
    const int h = xcd + 8 * sub;
    const int g2 = h >> 1;
    const int rel = g2 >> 2, kh = g2 & 3;
    const int m0 = ((h & 1) * 32 + m) * 64;
    constexpr int NP = 64;
    constexpr int NM = 32;

    const unsigned char* Bt = xgwp + ((size_t)rel * 256 + (size_t)kh * NP) * 16384;
    float* Cg = aggP + (((size_t)kh * Rc + rel) * D1c + m0) * 128;

    const int lst = (lane & 31) >> 4;
    const int lr2 = lane >> 5;
    const int fo  = (lane & 31) * 4;
    const int ch  = (fo & 63) >> 3;
    const int eo  = fo & 7;
    const float* aW = dif1 + ((size_t)(rel * D1c + m0 + w * 16 + lr2)) * S1c
                    + (size_t)kh * 4096 + fo;
    const unsigned char* bsrc = Bt + w * 4096 + lane * 16;

    f32x4 acc[2][4] = {};
    f32x4 a0[8], a1[8];

#define LOAD_A(ARR, M_) do { _Pragma("unroll") \
    for (int ri = 0; ri < 8; ri++) \
      ARR[ri] = __builtin_nontemporal_load( \
          (const f32x4*)(aW + (size_t)ri * 2 * S1c + (size_t)(M_) * 128)); \
  } while (0)

#define WRITE_A(ARR, NBUF) do { if (lst == (NBUF)) { _Pragma("unroll") \
    for (int ri = 0; ri < 8; ri++) { \
      const int row_ = w * 16 + ri * 2 + lr2; \
      bf16x4 cv_; \
      cv_[0] = (__bf16)ARR[ri].x; cv_[1] = (__bf16)ARR[ri].y; \
      cv_[2] = (__bf16)ARR[ri].z; cv_[3] = (__bf16)ARR[ri].w; \
      *(bf16x4*)&Abuf[(NBUF) * 4096 + row_ * 64 + ((ch ^ (row_ & 7)) * 8) + eo] = cv_; \
    } } } while (0)

    LOAD_A(a0, 0);
    {
      char* bd = (char*)Bbuf + w * 4096;
#pragma unroll
      for (int i = 0; i < 4; i++) glds16(bsrc + i * 1024, bd + i * 1024);
    }
    WRITE_A(a0, 0);
    LOAD_A(a1, 1);

#pragma unroll 1
    for (int g = 0; g < NP; ++g) {
      const int buf = g & 1, nbuf = buf ^ 1;
      asm volatile("s_waitcnt lgkmcnt(0)" ::: "memory");
      __builtin_amdgcn_s_barrier();
      __builtin_amdgcn_sched_barrier(0);
      if (g + 1 < NP) {
        const unsigned char* bs = bsrc + (size_t)(g + 1) * 16384;
        char* bd = (char*)Bbuf + nbuf * 16384 + w * 4096;
#pragma unroll
        for (int i = 0; i < 4; i++) glds16(bs + i * 1024, bd + i * 1024);
      }
      if (g + 1 < NP) {
        const int mw = (g + 1) >> 1;
        if ((mw & 1) == 0) { WRITE_A(a0, nbuf); }
        else               { WRITE_A(a1, nbuf); }
      }
      if (g & 1) {
        const int mn = (g + 3) >> 1;
        if (mn < NM) {
          if ((mn & 1) == 0) { LOAD_A(a0, mn); }
          else               { LOAD_A(a1, mn); }
        }
      }
      if (g < NP - 2)
        asm volatile("s_waitcnt vmcnt(12) lgkmcnt(0)" ::: "memory");
      else if (g == NP - 2)
        asm volatile("s_waitcnt vmcnt(4) lgkmcnt(0)" ::: "memory");
      else
        asm volatile("s_waitcnt vmcnt(0) lgkmcnt(0)" ::: "memory");
      __builtin_amdgcn_s_barrier();
      __builtin_amdgcn_sched_barrier(0);
      const __bf16* Ac = Abuf + buf * 4096;
      const __bf16* Bc = Bbuf + buf * 8192;
#pragma unroll
      for (int ks = 0; ks < 2; ks++) {
        const int cch = ks * 4 + (lane >> 4);
        bf16x8 af[2], bfr[4];
#pragma unroll
        for (int mi = 0; mi < 2; mi++) {
          int rr = mh * 32 + mi * 16 + (lane & 15);
          af[mi] = *(const bf16x8*)&Ac[rr * 64 + ((cch ^ (rr & 7)) * 8)];
        }
#pragma unroll
        for (int ni = 0; ni < 4; ni++) {
          int n = nh * 64 + ni * 16 + (lane & 15);
          bfr[ni] = *(const bf16x8*)&Bc[n * 64 + ((cch ^ (n & 7)) * 8)];
        }
#pragma unroll
        for (int mi = 0; mi < 2; mi++)
#pragma unroll
          for (int ni = 0; ni < 4; ni++)
            acc[mi][ni] = __builtin_amdgcn_mfma_f32_16x16x32_bf16(af[mi], bfr[ni], acc[mi][ni], 0, 0, 0);
      }
    }
#undef LOAD_A
#undef WRITE_A
#pragma unroll
    for (int mi = 0; mi < 2; mi++)
#pragma unroll
      for (int ni = 0; ni < 4; ni++) {
        const int col = nh * 64 + ni * 16 + (lane & 15);
#pragma unroll
        for (int j = 0; j < 4; j++) {
          const int rr = mh * 32 + mi * 16 + (lane >> 4) * 4 + j;
          Cg[(size_t)rr * 128 + col] = acc[mi][ni][j];
        }
      }
  } else {
    __bf16* Asm = (__bf16*)lds;
    __bf16* Bhs = (__bf16*)(lds + 8192);
    __bf16* Bls = (__bf16*)(lds + 24576);
    const int jb = blockIdx.x - 768;
    const int rel = jb >> 6, bx = jb & 63, s0 = bx * 64;
    const unsigned char* Bh = wp + (size_t)4 * 16384;
    const unsigned char* Bl = wp + (size_t)16 * 16384;

    const int arow = t >> 2, ak0 = (t & 3) * 16;
    const int row = s0 + arow;
    const size_t arowg = (size_t)srcn[rel * N0c + d2d1[(size_t)rel * D1c + row]];
    const float* aptr = feat + arowg * Fc + ak0;
    const int ac0 = ak0 >> 3;
    __bf16* asw0 = &Asm[arow * 64 + ((ac0    ) ^ (arow & 7)) * 8];
    __bf16* asw1 = &Asm[arow * 64 + ((ac0 + 1) ^ (arow & 7)) * 8];

    float4 a[16];
#pragma unroll
    for (int tl = 0; tl < 4; tl++)
#pragma unroll
      for (int j = 0; j < 4; j++) a[tl * 4 + j] = *(const float4*)(aptr + tl * 64 + 4 * j);

    f32x4 acc[2][4] = {};
    for (int tl = 0; tl < 4; ++tl) {
      asm volatile("s_waitcnt lgkmcnt(0)" ::: "memory");
      __builtin_amdgcn_s_barrier();
      __builtin_amdgcn_sched_barrier(0);
      {
        const unsigned char* bh = Bh + (size_t)tl * 16384 + w * 4096 + lane * 16;
        const unsigned char* bl = Bl + (size_t)tl * 16384 + w * 4096 + lane * 16;
        char* dh = (char*)Bhs + w * 4096;
        char* dl = (char*)Bls + w * 4096;
#pragma unroll
        for (int i = 0; i < 4; i++) glds16(bh + i * 1024, dh + i * 1024);
#pragma unroll
        for (int i = 0; i < 4; i++) glds16(bl + i * 1024, dl + i * 1024);
      }
      *(bf16x8*)asw0 = cvt2(a[tl * 4 + 0], a[tl * 4 + 1]);
      *(bf16x8*)asw1 = cvt2(a[tl * 4 + 2], a[tl * 4 + 3]);
      asm volatile("s_waitcnt vmcnt(0) lgkmcnt(0)" ::: "memory");
      __builtin_amdgcn_s_barrier();
      __builtin_amdgcn_sched_barrier(0);
#pragma unroll
      for (int ks = 0; ks < 2; ks++) {
        const int ch = ks * 4 + (lane >> 4);
        bf16x8 af[2], bh[4], bl[4];
#pragma unroll
        for (int mi = 0; mi < 2; mi++) {
          int r = mh * 32 + mi * 16 + (lane & 15);
          af[mi] = *(const bf16x8*)&Asm[r * 64 + ((ch ^ (r & 7)) * 8)];
        }
#pragma unroll
        for (int ni = 0; ni < 4; ni++) {
          int n = nh * 64 + ni * 16 + (lane & 15);
          bh[ni] = *(const bf16x8*)&Bhs[n * 64 + ((ch ^ (n & 7)) * 8)];
          bl[ni] = *(const bf16x8*)&Bls[n * 64 + ((ch ^ (n & 7)) * 8)];
        }
#pragma unroll
        for (int mi = 0; mi < 2; mi++)
#pragma unroll
          for (int ni = 0; ni < 4; ni++) {
            acc[mi][ni] = __builtin_amdgcn_mfma_f32_16x16x32_bf16(af[mi], bh[ni], acc[mi][ni], 0, 0, 0);
            acc[mi][ni] = __builtin_amdgcn_mfma_f32_16x16x32_bf16(af[mi], bl[ni], acc[mi][ni], 0, 0, 0);
          }
      }
    }
#pragma unroll
    for (int mi = 0; mi < 2; mi++)
#pragma unroll
      for (int ni = 0; ni < 4; ni++) {
        const int col = nh * 64 + ni * 16 + (lane & 15);
#pragma unroll
        for (int j = 0; j < 4; j++) {
          const int rr = mh * 32 + mi * 16 + (lane >> 4) * 4 + j;
          xdw[((size_t)rel * D1c + s0 + rr) * 128 + col] = acc[mi][ni][j];
        }
      }
  }
}

// ---------------------------------------------------------------------------
// gemm_big: C_partial[kh] = A[rel][m][k-slice] @ Bpanel   (GEMM2 only)
// ---------------------------------------------------------------------------
__global__ __launch_bounds__(256, 3)
void gemm_big(const float* __restrict__ A, const unsigned char* __restrict__ Bp,
              float* __restrict__ C, int M, int KTOT, int KH) {
  const int rel = blockIdx.z, kh = blockIdx.y, m0 = blockIdx.x * 64;
  const int t = threadIdx.x, lane = t & 63, w = t >> 6;
  const int KB = KTOT / KH, NT = KB >> 6;
  const int mh = w >> 1, nh = w & 1;

  const float* Ag = A + ((size_t)rel * M + m0) * KTOT + (size_t)kh * KB;
  const unsigned char* Bt = Bp + ((size_t)rel * (KTOT >> 6) + (size_t)kh * NT) * 16384;
  float* Cg = C + (((size_t)kh * Rc + rel) * M + m0) * 128;

  __shared__ __bf16 Asm[64 * 64];
  __shared__ __bf16 Bsm[2][128 * 64];

  f32x4 acc[2][4] = {};
  const int arow = t >> 2, ak0 = (t & 3) * 16;
  const float* aptr = Ag + (size_t)arow * KTOT + ak0;
  const int ac0 = ak0 >> 3;
  __bf16* asw0 = &Asm[arow * 64 + ((ac0    ) ^ (arow & 7)) * 8];
  __bf16* asw1 = &Asm[arow * 64 + ((ac0 + 1) ^ (arow & 7)) * 8];
  const unsigned char* bsrc = Bt + w * 4096 + lane * 16;

  float4 a0[4], a1[4];
#pragma unroll
  for (int j = 0; j < 4; j++) a0[j] = *(const float4*)(aptr + 4 * j);
  {
    char* bd = (char*)Bsm[0] + w * 4096;
#pragma unroll
    for (int i = 0; i < 4; i++) glds16(bsrc + i * 1024, bd + i * 1024);
  }

  for (int tl = 0; tl < NT; ++tl) {
    const int cur = tl & 1;
    asm volatile("s_waitcnt lgkmcnt(0)" ::: "memory");
    __builtin_amdgcn_s_barrier();
    __builtin_amdgcn_sched_barrier(0);
    if (tl + 1 < NT) {
      const unsigned char* bs = bsrc + (size_t)(tl + 1) * 16384;
      char* bd = (char*)Bsm[cur ^ 1] + w * 4096;
#pragma unroll
      for (int i = 0; i < 4; i++) glds16(bs + i * 1024, bd + i * 1024);
      const float* ap = aptr + (size_t)(tl + 1) * 64;
#pragma unroll
      for (int j = 0; j < 4; j++) a1[j] = *(const float4*)(ap + 4 * j);
    }
    *(bf16x8*)asw0 = cvt2(a0[0], a0[1]);
    *(bf16x8*)asw1 = cvt2(a0[2], a0[3]);
    if (tl + 1 < NT)
      asm volatile("s_waitcnt vmcnt(8) lgkmcnt(0)" ::: "memory");
    else
      asm volatile("s_waitcnt vmcnt(0) lgkmcnt(0)" ::: "memory");
    __builtin_amdgcn_s_barrier();
    __builtin_amdgcn_sched_barrier(0);
    const __bf16* Bc = Bsm[cur];
#pragma unroll
    for (int ks = 0; ks < 2; ks++) {
      const int ch = ks * 4 + (lane >> 4);
      bf16x8 af[2], bfr[4];
#pragma unroll
      for (int mi = 0; mi < 2; mi++) {
        int r = mh * 32 + mi * 16 + (lane & 15);
        af[mi] = *(const bf16x8*)&Asm[r * 64 + ((ch ^ (r & 7)) * 8)];
      }
#pragma unroll
      for (int ni = 0; ni < 4; ni++) {
        int n = nh * 64 + ni * 16 + (lane & 15);
        bfr[ni] = *(const bf16x8*)&Bc[n * 64 + ((ch ^ (n & 7)) * 8)];
      }
#pragma unroll
      for (int mi = 0; mi < 2; mi++)
#pragma unroll
        for (int ni = 0; ni < 4; ni++)
          acc[mi][ni] = __builtin_amdgcn_mfma_f32_16x16x32_bf16(af[mi], bfr[ni], acc[mi][ni], 0, 0, 0);
    }
#pragma unroll
    for (int j = 0; j < 4; j++) a0[j] = a1[j];
  }
#pragma unroll
  for (int mi = 0; mi < 2; mi++)
#pragma unroll
    for (int ni = 0; ni < 4; ni++) {
      const int col = nh * 64 + ni * 16 + (lane & 15);
#pragma unroll
      for (int j = 0; j < 4; j++) {
        const int r = mh * 32 + mi * 16 + (lane >> 4) * 4 + j;
        Cg[(size_t)r * 128 + col] = acc[mi][ni][j];
      }
    }
}

// ---------------------------------------------------------------------------
// c1_l2: FUSED combine1 + BOTH layer-2 projections (R7-proven form).
// ---------------------------------------------------------------------------
__global__ __launch_bounds__(256, 3)
void c1_l2(const float* __restrict__ aggP, const float* __restrict__ xdw,
           const float* __restrict__ attv, const unsigned char* __restrict__ wp,
           float* __restrict__ escore1, float* __restrict__ esum,
           float* __restrict__ P, float* __restrict__ Q) {
  const int rel = blockIdx.y, d0 = blockIdx.x * 64;
  const int t = threadIdx.x, lane = t & 63, w = t >> 6;
  const int mh = w >> 1, nh = w & 1;

  __shared__ __bf16 Asm[64 * 128];
  __shared__ __bf16 Bhs[128 * 64];
  __shared__ __bf16 Bls[128 * 64];
  __shared__ float  sred[64];

  const int r = t >> 2, c0 = (t & 3) * 32;
  float4 x0[8];
  {
    const size_t base = ((size_t)rel * D1c + d0 + r) * 128 + c0;
#pragma unroll
    for (int j = 0; j < 8; j++) x0[j] = *(const float4*)(xdw + base + 4 * j);
#pragma unroll
    for (int p2 = 0; p2 < KH1; p2++) {
      const float* ap = aggP + (((size_t)p2 * Rc + rel) * D1c + d0 + r) * 128 + c0;
#pragma unroll
      for (int j = 0; j < 8; j++) {
        float4 u = *(const float4*)(ap + 4 * j);
        x0[j].x += u.x; x0[j].y += u.y; x0[j].z += u.z; x0[j].w += u.w;
      }
    }
  }
  float sp = 0.f;
#pragma unroll
  for (int j = 0; j < 8; j++) {
    sp += x0[j].x * attv[c0 + 4 * j]     + x0[j].y * attv[c0 + 4 * j + 1]
        + x0[j].z * attv[c0 + 4 * j + 2] + x0[j].w * attv[c0 + 4 * j + 3];
  }
  sp += __shfl_xor(sp, 1); sp += __shfl_xor(sp, 2);
  const float e = expf(sp);
  if ((t & 3) == 0) { escore1[(size_t)rel * D1c + d0 + r] = e; sred[r] = e; }
  const int ch0 = (t & 3) * 4;
#pragma unroll
  for (int q = 0; q < 4; q++) {
    *(bf16x8*)&Asm[r * 128 + (((ch0 + q) ^ (r & 7)) * 8)] = cvt2(x0[2 * q], x0[2 * q + 1]);
  }
  __syncthreads();
  if (t < 64) {
    float v = sred[t];
    v += __shfl_down(v, 32); v += __shfl_down(v, 16); v += __shfl_down(v, 8);
    v += __shfl_down(v, 4);  v += __shfl_down(v, 2);  v += __shfl_down(v, 1);
    if (t == 0) atomicAdd(esum + rel, v);
  }
  f32x4 accP[2][4] = {}, accQ[2][4] = {};
#pragma unroll
  for (int z = 0; z < 2; z++) {
#pragma unroll
    for (int tl = 0; tl < 2; tl++) {
      if (!(z == 0 && tl == 0)) {
        asm volatile("s_waitcnt lgkmcnt(0)" ::: "memory");
        __builtin_amdgcn_s_barrier();
        __builtin_amdgcn_sched_barrier(0);
      }
      {
        const unsigned char* bh = wp + (size_t)(8 + z * 2 + tl) * 16384 + w * 4096 + lane * 16;
        const unsigned char* bl = wp + (size_t)(20 + z * 2 + tl) * 16384 + w * 4096 + lane * 16;
        char* dh = (char*)Bhs + w * 4096;
        char* dl = (char*)Bls + w * 4096;
#pragma unroll
        for (int i = 0; i < 4; i++) glds16(bh + i * 1024, dh + i * 1024);
#pragma unroll
        for (int i = 0; i < 4; i++) glds16(bl + i * 1024, dl + i * 1024);
      }
      asm volatile("s_waitcnt vmcnt(0) lgkmcnt(0)" ::: "memory");
      __builtin_amdgcn_s_barrier();
      __builtin_amdgcn_sched_barrier(0);
      f32x4 (*acc)[4] = z ? accQ : accP;
#pragma unroll
      for (int ks = 0; ks < 2; ks++) {
        const int lch = ks * 4 + (lane >> 4);
        const int ch  = tl * 8 + lch;
        bf16x8 af[2], bh[4], bl[4];
#pragma unroll
        for (int mi = 0; mi < 2; mi++) {
          int rr = mh * 32 + mi * 16 + (lane & 15);
          af[mi] = *(const bf16x8*)&Asm[rr * 128 + ((ch ^ (rr & 7)) * 8)];
        }
#pragma unroll
        for (int ni = 0; ni < 4; ni++) {
          int n = nh * 64 + ni * 16 + (lane & 15);
          bh[ni] = *(const bf16x8*)&Bhs[n * 64 + ((lch ^ (n & 7)) * 8)];
          bl[ni] = *(const bf16x8*)&Bls[n * 64 + ((lch ^ (n & 7)) * 8)];
        }
#pragma unroll
        for (int mi = 0; mi < 2; mi++)
#pragma unroll
          for (int ni = 0; ni < 4; ni++) {
            acc[mi][ni] = __builtin_amdgcn_mfma_f32_16x16x32_bf16(af[mi], bh[ni], acc[mi][ni], 0, 0, 0);
            acc[mi][ni] = __builtin_amdgcn_mfma_f32_16x16x32_bf16(af[mi], bl[ni], acc[mi][ni], 0, 0, 0);
          }
      }
    }
  }
#pragma unroll
  for (int mi = 0; mi < 2; mi++)
#pragma unroll
    for (int ni = 0; ni < 4; ni++) {
      const int col = nh * 64 + ni * 16 + (lane & 15);
#pragma unroll
      for (int j = 0; j < 4; j++) {
        const int rr = mh * 32 + mi * 16 + (lane >> 4) * 4 + j;
        P[((size_t)rel * D1c + d0 + rr) * 128 + col] = accP[mi][ni][j];
        Q[((size_t)rel * D1c + d0 + rr) * 128 + col] = accQ[mi][ni][j];
      }
    }
}

// ---------------------------------------------------------------------------
// pgpack: PG panel <- gather P rows via d2s2, scale by att1, bf16 packed.
// ---------------------------------------------------------------------------
__global__ __launch_bounds__(256, 2)
void pgpack(const float* __restrict__ P, const int* __restrict__ d2s2,
            const float* __restrict__ escore1, const float* __restrict__ esum,
            unsigned char* __restrict__ PGp) {
  const int rel = blockIdx.y, kb = blockIdx.x, t = threadIdx.x;
  const float inv1 = 1.0f / esum[rel];
  __shared__ __bf16 sm[64][136];
  {
    const int kl = t >> 2, c0 = (t & 3) * 32;
    const int sr = d2s2[rel * S2c + kb * 64 + kl];
    const float sc = escore1[(size_t)rel * D1c + sr] * inv1;
    const float4* p = (const float4*)(P + ((size_t)rel * D1c + sr) * 128 + c0);
#pragma unroll
    for (int j = 0; j < 4; j++) {
      float4 v0 = p[2 * j], v1 = p[2 * j + 1];
      v0.x *= sc; v0.y *= sc; v0.z *= sc; v0.w *= sc;
      v1.x *= sc; v1.y *= sc; v1.z *= sc; v1.w *= sc;
      *(bf16x8*)&sm[kl][c0 + 8 * j] = cvt2(v0, v1);
    }
  }
  __syncthreads();
  if (t < 128) {
    const int n = t;
    unsigned char* dst = PGp + ((size_t)(rel * (S2c >> 6) + kb)) * 16384;
#pragma unroll
    for (int ch = 0; ch < 8; ch++) {
      bf16x8 o;
#pragma unroll
      for (int e = 0; e < 8; e++) o[e] = sm[ch * 8 + e][n];
      *(bf16x8*)(dst + n * 128 + ((ch ^ (n & 7)) * 16)) = o;
    }
  }
}

// ---------------------------------------------------------------------------
// combine2: h2 = sum_kh2 aggP2 + att1[qr]*Q[qr] ; e2 = exp(h2 . attv)
// ---------------------------------------------------------------------------
__global__ __launch_bounds__(128, 4)
void combine2(const float* __restrict__ aggP2, const float* __restrict__ Q,
              const int* __restrict__ d2d2, const float* __restrict__ attv,
              const float* __restrict__ escore1, const float* __restrict__ esum,
              float* __restrict__ h2, float* __restrict__ escore2) {
  const int rel = blockIdx.y, d0 = blockIdx.x * 8, t = threadIdx.x;
  const float inv1 = 1.0f / esum[rel];
  float acc[8];
#pragma unroll
  for (int i = 0; i < 8; i++) {
    const int d = d0 + i;
    const int qr = d2d2[rel * D2c + d];
    const float qs = escore1[(size_t)rel * D1c + qr] * inv1;
    float v = Q[((size_t)rel * D1c + qr) * 128 + t] * qs;
#pragma unroll
    for (int p = 0; p < KH2; p++)
      v += aggP2[(((size_t)p * Rc + rel) * D2c + d) * 128 + t];
    acc[i] = v;
    h2[((size_t)rel * D2c + d) * 128 + t] = v;
  }
  const float avt = attv[t];
  __shared__ float sred[2][8];
#pragma unroll
  for (int i = 0; i < 8; i++) {
    float p = acc[i] * avt;
    p += __shfl_down(p, 32); p += __shfl_down(p, 16); p += __shfl_down(p, 8);
    p += __shfl_down(p, 4);  p += __shfl_down(p, 2);  p += __shfl_down(p, 1);
    if ((t & 63) == 0) sred[t >> 6][i] = p;
  }
  __syncthreads();
  if (t < 8) {
    const float e2 = expf(sred[0][t] + sred[1][t]);
    escore2[rel * D2c + d0 + t] = e2;
    float v = e2;
    v += __shfl_down(v, 4); v += __shfl_down(v, 2); v += __shfl_down(v, 1);
    if (t == 0) atomicAdd((float*)esum + 4 + rel, v);
  }
}

// ---------------------------------------------------------------------------
// k9: summed = sum_r h2 * att2 ; l2-normalize; logits = normed@cw; softmax
// ---------------------------------------------------------------------------
__global__ __launch_bounds__(128, 4)
void k9_final(const float* __restrict__ h2, const float* __restrict__ escore2,
              const float* __restrict__ esum, const float* __restrict__ cw,
              float* __restrict__ out) {
  const int d = blockIdx.x, t = threadIdx.x;
  float v = 0.f;
#pragma unroll
  for (int r = 0; r < Rc; r++) {
    const float att = escore2[r * D2c + d] / esum[4 + r];
    v += h2[((size_t)r * D2c + d) * Hc + t] * att;
  }
  float ss = v * v;
  ss += __shfl_down(ss, 32); ss += __shfl_down(ss, 16); ss += __shfl_down(ss, 8);
  ss += __shfl_down(ss, 4);  ss += __shfl_down(ss, 2);  ss += __shfl_down(ss, 1);
  __shared__ float sr[3][2];
  if ((t & 63) == 0) sr[0][t >> 6] = ss;
  __syncthreads();
  const float tot = sr[0][0] + sr[0][1];
  const float inv = rsqrtf(fmaxf(tot, 1e-12f));
  const float nv = v * inv;
  float p0 = nv * cw[t * 2], p1 = nv * cw[t * 2 + 1];
  p0 += __shfl_down(p0, 32); p0 += __shfl_down(p0, 16); p0 += __shfl_down(p0, 8);
  p0 += __shfl_down(p0, 4);  p0 += __shfl_down(p0, 2);  p0 += __shfl_down(p0, 1);
  p1 += __shfl_down(p1, 32); p1 += __shfl_down(p1, 16); p1 += __shfl_down(p1, 8);
  p1 += __shfl_down(p1, 4);  p1 += __shfl_down(p1, 2);  p1 += __shfl_down(p1, 1);
  if ((t & 63) == 0) { sr[1][t >> 6] = p0; sr[2][t >> 6] = p1; }
  __syncthreads();
  if (t == 0) {
    const float l0 = sr[1][0] + sr[1][1];
    const float l1 = sr[2][0] + sr[2][1];
    const float m = fmaxf(l0, l1);
    const float e0 = expf(l0 - m), e1 = expf(l1 - m);
    const float is = 1.0f / (e0 + e1);
    out[d * 2 + 0] = e0 * is;
    out[d * 2 + 1] = e1 * is;
  }
}

// ---------------------------------------------------------------------------
extern "C" void kernel_launch(void* const* d_in, const int* in_sizes, int n_in,
                              void* d_out, int out_size, void* d_ws, size_t ws_size,
                              hipStream_t stream) {
  (void)in_sizes; (void)n_in; (void)out_size; (void)ws_size;
  const float* feat = (const float*)d_in[0];
  const int*   srcn = (const int*)d_in[1];
  const int*   d2s1 = (const int*)d_in[2];
  const int*   d2d1 = (const int*)d_in[3];
  const float* dif1 = (const float*)d_in[4];
  const int*   d2s2 = (const int*)d_in[5];
  const int*   d2d2 = (const int*)d_in[6];
  const float* dif2 = (const float*)d_in[7];
  const float* w1   = (const float*)d_in[8];
  const float* w2   = (const float*)d_in[9];
  // d_in[10] relation_vectors: softmax-invariant constant -> unused.
  const float* attv = (const float*)d_in[11];
  const float* cw   = (const float*)d_in[12];
  float* out = (float*)d_out;

  char* p = (char*)d_ws;
  auto take = [&](size_t n) { char* r = p; p += (n + 255) & ~(size_t)255; return r; };
  unsigned char* wp   = (unsigned char*)take(24 * 16384);
  unsigned char* xgwp = (unsigned char*)take((size_t)Rc * 256 * 16384);   // 12.6 MB (reused as P|Q)
  float* xdw    = (float*)take((size_t)Rc * D1c * 128 * 4);
  float* aggP   = (float*)take((size_t)KH1 * Rc * D1c * 128 * 4);         // 25.2 MB (reused as aggP2)
  float* escore1= (float*)take((size_t)Rc * D1c * 4);
  float* esum   = (float*)take(256);
  unsigned char* PGp = (unsigned char*)take((size_t)Rc * 64 * 16384);
  float* h2     = (float*)take((size_t)Rc * D2c * 128 * 4);
  float* escore2= (float*)take((size_t)Rc * D2c * 4);
  float* P = (float*)xgwp;                       // alias after big1p
  float* Q = P + (size_t)Rc * D1c * 128;
  float* aggP2 = aggP;                           // alias after c1_l2

  wpack<<<dim3(12, 2), 256, 0, stream>>>(w1, w2, wp, esum);
  gg0<<<dim3(256, Rc), 256, 0, stream>>>(feat, srcn, d2s1, wp, xgwp);
  big1p<<<960, 256, 0, stream>>>(dif1, xgwp, aggP, feat, srcn, d2d1, wp, xdw);
  c1_l2<<<dim3(D1c / 64, Rc), 256, 0, stream>>>(aggP, xdw, attv, wp, escore1, esum, P, Q);
  pgpack<<<dim3(S2c / 64, Rc), 256, 0, stream>>>(P, d2s2, escore1, esum, PGp);
  gemm_big<<<dim3(D2c / 64, KH2, Rc), 256, 0, stream>>>(dif2, PGp, aggP2, D2c, S2c, KH2);
  combine2<<<dim3(D2c / 8, Rc), 128, 0, stream>>>(aggP2, Q, d2d2, attv, escore1, esum, h2, escore2);
  k9_final<<<D2c, 128, 0, stream>>>(h2, escore2, esum, cw, out);
}